// Round 1
// baseline (333.593 us; speedup 1.0000x reference)
//
#include <hip/hip_runtime.h>
#include <stdint.h>

#define DIM 128
#define RNB 32
#define EFS 64
#define KTOP 10
#define INFD 1e30f

typedef unsigned long long u64;

__device__ __forceinline__ u64 shflx64(u64 v, int m) {
    return (u64)__shfl_xor((long long)v, m, 64);
}

// Bitonic sort of 128 u64 keys held 2-per-lane across one 64-lane wave.
// e0 holds element index lane, e1 holds element index lane+64.
// Keys embed the original index in the low 32 bits -> result is identical
// to a stable sort on the high 32 bits.
__device__ __forceinline__ void bitonic128(u64 &e0, u64 &e1, int lane) {
    #pragma unroll
    for (int k = 2; k <= 128; k <<= 1) {
        #pragma unroll
        for (int j = k >> 1; j >= 1; j >>= 1) {
            if (j == 64) {
                // partner is the other register on the same lane; ascending
                u64 lo = e0 < e1 ? e0 : e1;
                u64 hi = e0 < e1 ? e1 : e0;
                e0 = lo; e1 = hi;
            } else {
                u64 o0 = shflx64(e0, j);
                u64 o1 = shflx64(e1, j);
                int i0 = lane, i1 = lane + 64;
                bool keepmin0 = ((i0 & k) == 0) == ((i0 & j) == 0);
                bool keepmin1 = ((i1 & k) == 0) == ((i1 & j) == 0);
                e0 = keepmin0 ? (e0 < o0 ? e0 : o0) : (e0 > o0 ? e0 : o0);
                e1 = keepmin1 ? (e1 < o1 ? e1 : o1) : (e1 > o1 ? e1 : o1);
            }
        }
    }
}

// Exact emulation of the reference _merge over n (64 or 96) slots in LDS.
// Wave 0 does the work; all 4 waves must call (contains __syncthreads).
__device__ __forceinline__ void merge96(int n, int lane, int wave,
                                        int* ids_s, float* dst_s, int* exp_s,
                                        int* ids2, float* dst2, int* exp2) {
    __syncthreads();  // make all ids/dst/exp writes visible to wave 0
    if (wave == 0) {
        // ---- stable sort 1: key = id*2 + (1 - expanded), tie = original idx
        int i1 = lane + 64;
        u64 e0 = ((u64)(uint32_t)(ids_s[lane] * 2 + (exp_s[lane] ? 0 : 1)) << 32) | (uint32_t)lane;
        u64 e1 = ~0ULL;
        if (i1 < n)
            e1 = ((u64)(uint32_t)(ids_s[i1] * 2 + (exp_s[i1] ? 0 : 1)) << 32) | (uint32_t)i1;
        bitonic128(e0, e1, lane);

        // gather payloads into rank order (rank lane in e0, rank lane+64 in e1)
        int id0 = -1, id1 = -1; float d0 = INFD, d1 = INFD; int x0 = 1, x1 = 1;
        { int p = (int)(e0 & 0xffffffffu); id0 = ids_s[p]; d0 = dst_s[p]; x0 = exp_s[p]; }
        if (e1 != ~0ULL) { int p = (int)(e1 & 0xffffffffu); id1 = ids_s[p]; d1 = dst_s[p]; x1 = exp_s[p]; }

        // ---- dup kill: dup[i] = ids[i] == ids[i-1] in rank order
        int prev0 = __shfl_up(id0, 1);
        int top0  = __shfl(id0, 63);
        int prev1 = __shfl_up(id1, 1);
        bool dup0 = (lane > 0) && (id0 == prev0);
        bool dup1 = (i1 < n) && (id1 == ((lane == 0) ? top0 : prev1));
        if (dup0) { d0 = INFD; x0 = 1; }
        if (dup1) { d1 = INFD; x1 = 1; }

        // stash rank-ordered intermediates for the post-sort gather
        ids2[lane] = id0; dst2[lane] = d0; exp2[lane] = x0;
        ids2[i1]   = id1; dst2[i1]   = d1; exp2[i1]   = x1;

        // ---- stable sort 2: key = dist (f32 bits, all >= 0), tie = rank
        u64 f0 = ((u64)__float_as_uint(d0) << 32) | (uint32_t)lane;
        u64 f1 = (i1 < n) ? (((u64)__float_as_uint(d1) << 32) | (uint32_t)i1) : ~0ULL;
        bitonic128(f0, f1, lane);

        // keep best 64 (ranks 0..63 live in e0 slots)
        int pf = (int)(f0 & 0xffffffffu);
        int idf = ids2[pf]; float df = dst2[pf]; int xf = exp2[pf];
        ids_s[lane] = idf; dst_s[lane] = df; exp_s[lane] = xf;
    }
    __syncthreads();
}

extern "C" __global__ __launch_bounds__(256)
void nsw_search(const float* __restrict__ query,
                const float* __restrict__ storage,
                const int* __restrict__ indices,
                const int* __restrict__ entry,
                float* __restrict__ out,
                int B) {
    const int b = blockIdx.x;
    const int tid = threadIdx.x;
    const int lane = tid & 63;
    const int wave = tid >> 6;

    __shared__ __align__(16) float q_s[DIM];
    __shared__ int   ids_s[96];
    __shared__ float dst_s[96];
    __shared__ int   exp_s[96];
    __shared__ int   ids2[128];
    __shared__ float dst2[128];
    __shared__ int   exp2[128];
    __shared__ int   node_sh;

    if (tid < DIM) q_s[tid] = query[(size_t)b * DIM + tid];
    if (tid < EFS) { ids_s[tid] = entry[(size_t)b * EFS + tid]; exp_s[tid] = 0; }
    __syncthreads();

    // ---- initial distances: 64 entry points, 4 threads each (32 dims/thread)
    {
        int g = tid >> 2, sub = tid & 3;
        int id = ids_s[g];
        const float4* row = (const float4*)(storage + (size_t)id * DIM);
        const float4* q4 = (const float4*)q_s;
        float acc = 0.f;
        #pragma unroll
        for (int c = 0; c < 8; ++c) {
            float4 v = row[sub * 8 + c];
            float4 qv = q4[sub * 8 + c];
            float dx = v.x - qv.x; acc = fmaf(dx, dx, acc);
            dx = v.y - qv.y; acc = fmaf(dx, dx, acc);
            dx = v.z - qv.z; acc = fmaf(dx, dx, acc);
            dx = v.w - qv.w; acc = fmaf(dx, dx, acc);
        }
        acc += __shfl_xor(acc, 1);
        acc += __shfl_xor(acc, 2);
        if (sub == 0) dst_s[g] = acc;
    }

    merge96(64, lane, wave, ids_s, dst_s, exp_s, ids2, dst2, exp2);

    // ---- EF best-first expansion steps
    for (int step = 0; step < EFS; ++step) {
        // select first unexpanded slot (beam is dist-sorted => argmin semantics)
        if (wave == 0) {
            bool open = (exp_s[lane] == 0);
            u64 m = __ballot(open);
            if (lane == 0) {
                int sel = m ? (int)(__ffsll(m) - 1) : 0;
                exp_s[sel] = 1;
                node_sh = ids_s[sel];
            }
        }
        __syncthreads();
        int node = node_sh;
        if (tid < RNB) {
            ids_s[64 + tid] = indices[(size_t)node * RNB + tid];
            exp_s[64 + tid] = 0;
        }
        __syncthreads();

        // distances: 32 neighbors, 8 threads each (16 dims/thread)
        {
            int g = tid >> 3, sub = tid & 7;
            int id = ids_s[64 + g];
            const float4* row = (const float4*)(storage + (size_t)id * DIM);
            const float4* q4 = (const float4*)q_s;
            float acc = 0.f;
            #pragma unroll
            for (int c = 0; c < 4; ++c) {
                float4 v = row[sub * 4 + c];
                float4 qv = q4[sub * 4 + c];
                float dx = v.x - qv.x; acc = fmaf(dx, dx, acc);
                dx = v.y - qv.y; acc = fmaf(dx, dx, acc);
                dx = v.z - qv.z; acc = fmaf(dx, dx, acc);
                dx = v.w - qv.w; acc = fmaf(dx, dx, acc);
            }
            acc += __shfl_xor(acc, 1);
            acc += __shfl_xor(acc, 2);
            acc += __shfl_xor(acc, 4);
            if (sub == 0) dst_s[64 + g] = acc;
        }

        merge96(96, lane, wave, ids_s, dst_s, exp_s, ids2, dst2, exp2);
    }

    // ---- outputs: ids (as float, exact for id < 2^24) then dists
    if (tid < KTOP) {
        out[(size_t)b * KTOP + tid] = (float)ids_s[tid];
        out[(size_t)B * KTOP + (size_t)b * KTOP + tid] = dst_s[tid];
    }
}

extern "C" void kernel_launch(void* const* d_in, const int* in_sizes, int n_in,
                              void* d_out, int out_size, void* d_ws, size_t ws_size,
                              hipStream_t stream) {
    const float* query   = (const float*)d_in[0];
    const float* storage = (const float*)d_in[1];
    const int*   indices = (const int*)d_in[2];
    const int*   entry   = (const int*)d_in[3];
    int B = in_sizes[0] / DIM;
    float* out = (float*)d_out;
    nsw_search<<<B, 256, 0, stream>>>(query, storage, indices, entry, out, B);
}

// Round 2
// 294.775 us; speedup vs baseline: 1.1317x; 1.1317x over previous
//
#include <hip/hip_runtime.h>
#include <stdint.h>

#define DIM 128
#define RNB 32
#define EFS 64
#define KTOP 10
#define INFD 1e30f

typedef unsigned long long u64;

__device__ __forceinline__ u64 shflx64(u64 v, int m) {
    return (u64)__shfl_xor((long long)v, m, 64);
}
__device__ __forceinline__ u64 shfl64(u64 v, int src) {
    return (u64)__shfl((long long)v, src, 64);
}

// ---------------- exact slow-path merge (validated round 1) ----------------
__device__ __forceinline__ void bitonic128(u64 &e0, u64 &e1, int lane) {
    #pragma unroll
    for (int k = 2; k <= 128; k <<= 1) {
        #pragma unroll
        for (int j = k >> 1; j >= 1; j >>= 1) {
            if (j == 64) {
                u64 lo = e0 < e1 ? e0 : e1;
                u64 hi = e0 < e1 ? e1 : e0;
                e0 = lo; e1 = hi;
            } else {
                u64 o0 = shflx64(e0, j);
                u64 o1 = shflx64(e1, j);
                int i0 = lane, i1 = lane + 64;
                bool keepmin0 = ((i0 & k) == 0) == ((i0 & j) == 0);
                bool keepmin1 = ((i1 & k) == 0) == ((i1 & j) == 0);
                e0 = keepmin0 ? (e0 < o0 ? e0 : o0) : (e0 > o0 ? e0 : o0);
                e1 = keepmin1 ? (e1 < o1 ? e1 : o1) : (e1 > o1 ? e1 : o1);
            }
        }
    }
}

__device__ __forceinline__ void merge_slow(int n, int lane,
                                           int* ids_s, float* dst_s, int* exp_s,
                                           int* ids2, float* dst2, int* exp2) {
    __syncthreads();
    {
        int i1 = lane + 64;
        u64 e0 = ((u64)(uint32_t)(ids_s[lane] * 2 + (exp_s[lane] ? 0 : 1)) << 32) | (uint32_t)lane;
        u64 e1 = ~0ULL;
        if (i1 < n)
            e1 = ((u64)(uint32_t)(ids_s[i1] * 2 + (exp_s[i1] ? 0 : 1)) << 32) | (uint32_t)i1;
        bitonic128(e0, e1, lane);

        int id0 = -1, id1 = -1; float d0 = INFD, d1 = INFD; int x0 = 1, x1 = 1;
        { int p = (int)(e0 & 0xffffffffu); id0 = ids_s[p]; d0 = dst_s[p]; x0 = exp_s[p]; }
        if (e1 != ~0ULL) { int p = (int)(e1 & 0xffffffffu); id1 = ids_s[p]; d1 = dst_s[p]; x1 = exp_s[p]; }

        int prev0 = __shfl_up(id0, 1);
        int top0  = __shfl(id0, 63);
        int prev1 = __shfl_up(id1, 1);
        bool dup0 = (lane > 0) && (id0 == prev0);
        bool dup1 = (i1 < n) && (id1 == ((lane == 0) ? top0 : prev1));
        if (dup0) { d0 = INFD; x0 = 1; }
        if (dup1) { d1 = INFD; x1 = 1; }

        ids2[lane] = id0; dst2[lane] = d0; exp2[lane] = x0;
        ids2[i1]   = id1; dst2[i1]   = d1; exp2[i1]   = x1;

        u64 f0 = ((u64)__float_as_uint(d0) << 32) | (uint32_t)lane;
        u64 f1 = (i1 < n) ? (((u64)__float_as_uint(d1) << 32) | (uint32_t)i1) : ~0ULL;
        bitonic128(f0, f1, lane);

        int pf = (int)(f0 & 0xffffffffu);
        int idf = ids2[pf]; float df = dst2[pf]; int xf = exp2[pf];
        __syncthreads();
        ids_s[lane] = idf; dst_s[lane] = df; exp_s[lane] = xf;
    }
    __syncthreads();
}

// ---------------------------------------------------------------------------
extern "C" __global__ __launch_bounds__(64)
void nsw_search(const float* __restrict__ query,
                const float* __restrict__ storage,
                const int* __restrict__ indices,
                const int* __restrict__ entry,
                float* __restrict__ out,
                int B) {
    const int b = blockIdx.x;
    const int lane = threadIdx.x;  // 0..63, single wave

    __shared__ __align__(16) float q_s[DIM];
    __shared__ int   ids_s[96];
    __shared__ float dst_s[96];
    __shared__ int   exp_s[96];
    __shared__ int   ids2[128];
    __shared__ float dst2[128];
    __shared__ int   exp2[128];
    __shared__ u64   nkey_l[32];

    q_s[lane]      = query[(size_t)b * DIM + lane];
    q_s[64 + lane] = query[(size_t)b * DIM + 64 + lane];
    ids_s[lane] = entry[(size_t)b * EFS + lane];
    exp_s[lane] = 0;
    __syncthreads();

    // ---- initial distances: replicate round-1 chunking exactly
    // (virtual tid = p*64+lane over 256: g = vt>>2, sub = vt&3, c=0..7, tree xor 1,2)
    #pragma unroll
    for (int p = 0; p < 4; ++p) {
        int g = p * 16 + (lane >> 2), sub = lane & 3;
        int id = ids_s[g];
        const float4* row = (const float4*)(storage + (size_t)id * DIM);
        const float4* q4 = (const float4*)q_s;
        float acc = 0.f;
        #pragma unroll
        for (int c = 0; c < 8; ++c) {
            float4 v = row[sub * 8 + c];
            float4 qv = q4[sub * 8 + c];
            float dx = v.x - qv.x; acc = fmaf(dx, dx, acc);
            dx = v.y - qv.y; acc = fmaf(dx, dx, acc);
            dx = v.z - qv.z; acc = fmaf(dx, dx, acc);
            dx = v.w - qv.w; acc = fmaf(dx, dx, acc);
        }
        acc += __shfl_xor(acc, 1);
        acc += __shfl_xor(acc, 2);
        if (sub == 0) dst_s[g] = acc;
    }

    merge_slow(64, lane, ids_s, dst_s, exp_s, ids2, dst2, exp2);

    // beam -> registers (sorted ascending by composite key; invariant)
    int   bid = ids_s[lane];
    float bds = dst_s[lane];
    int   bex = exp_s[lane];

    // q chunk for step distances (sub = lane&7, float4s sub*4 .. sub*4+3)
    float4 qv0, qv1, qv2, qv3;
    {
        const float4* q4 = (const float4*)q_s;
        int sub = lane & 7;
        qv0 = q4[sub * 4 + 0]; qv1 = q4[sub * 4 + 1];
        qv2 = q4[sub * 4 + 2]; qv3 = q4[sub * 4 + 3];
    }

    for (int step = 0; step < EFS; ++step) {
        // ---- select: first open slot (beam sorted => argmin semantics)
        u64 open = __ballot(bex == 0);
        int sel = open ? (int)(__ffsll(open) - 1) : 0;
        int node = __shfl(bid, sel);
        if (lane == sel) bex = 1;

        // ---- neighbors
        if (lane < RNB) {
            ids_s[64 + lane] = indices[(size_t)node * RNB + lane];
        }
        __syncthreads();

        // ---- distances: replicate round-1 chunking (g = vt>>3, sub = vt&7,
        // c=0..3, tree xor 1,2,4) via 4 passes of 8 neighbors
        #pragma unroll
        for (int p = 0; p < 4; ++p) {
            int g = p * 8 + (lane >> 3), sub = lane & 7;
            int id = ids_s[64 + g];
            const float4* row = (const float4*)(storage + (size_t)id * DIM) + sub * 4;
            float acc = 0.f;
            float4 v;
            v = row[0];
            { float dx = v.x - qv0.x; acc = fmaf(dx, dx, acc);
              dx = v.y - qv0.y; acc = fmaf(dx, dx, acc);
              dx = v.z - qv0.z; acc = fmaf(dx, dx, acc);
              dx = v.w - qv0.w; acc = fmaf(dx, dx, acc); }
            v = row[1];
            { float dx = v.x - qv1.x; acc = fmaf(dx, dx, acc);
              dx = v.y - qv1.y; acc = fmaf(dx, dx, acc);
              dx = v.z - qv1.z; acc = fmaf(dx, dx, acc);
              dx = v.w - qv1.w; acc = fmaf(dx, dx, acc); }
            v = row[2];
            { float dx = v.x - qv2.x; acc = fmaf(dx, dx, acc);
              dx = v.y - qv2.y; acc = fmaf(dx, dx, acc);
              dx = v.z - qv2.z; acc = fmaf(dx, dx, acc);
              dx = v.w - qv2.w; acc = fmaf(dx, dx, acc); }
            v = row[3];
            { float dx = v.x - qv3.x; acc = fmaf(dx, dx, acc);
              dx = v.y - qv3.y; acc = fmaf(dx, dx, acc);
              dx = v.z - qv3.z; acc = fmaf(dx, dx, acc);
              dx = v.w - qv3.w; acc = fmaf(dx, dx, acc); }
            acc += __shfl_xor(acc, 1);
            acc += __shfl_xor(acc, 2);
            acc += __shfl_xor(acc, 4);
            if (sub == 0) dst_s[64 + g] = acc;
        }
        __syncthreads();

        // ---- INF tombstone in beam? (only then can beam ids collide)
        bool has_inf = __ballot(bds >= INFD) != 0;

        if (has_inf) {
            // exact general path (rare / early-only)
            ids_s[lane] = bid; dst_s[lane] = bds; exp_s[lane] = bex;
            if (lane < RNB) exp_s[64 + lane] = 0;
            merge_slow(96, lane, ids_s, dst_s, exp_s, ids2, dst2, exp2);
            bid = ids_s[lane]; bds = dst_s[lane]; bex = exp_s[lane];
            continue;
        }

        // ---- fast path -----------------------------------------------------
        int   nid = (lane < RNB) ? ids_s[64 + lane] : -1;
        float ndt = (lane < RNB) ? dst_s[64 + lane] : INFD;

        // kills: new j killed iff id matches ANY beam slot (beam always wins)
        // or an earlier new slot. 32 scalar ballots, fully pipelined.
        unsigned killmask = 0;
        #pragma unroll
        for (int j = 0; j < RNB; ++j) {
            int idj = __shfl(nid, j);
            u64 beq = __ballot(bid == idj);
            u64 neq = __ballot(nid == idj);
            u64 kj = beq | (neq & ((1ull << j) - 1ull));
            killmask |= (kj ? 1u : 0u) << j;
        }
        bool kill = (lane < RNB) && ((killmask >> lane) & 1u);

        // composite key: (dist | key1=id*2+(1-exp) | slot_idx) — reproduces
        // the reference's stable two-sort exactly (idrank == (key1,idx) order)
        float dk = kill ? INFD : ndt;
        u64 nkey = ((u64)__float_as_uint(dk) << 27)
                 | ((u64)(unsigned)(nid * 2 + 1) << 7)
                 | (unsigned)(64 + lane);

        // rank-sort the 32 new keys (pipelined broadcasts, no dependent chain)
        int rank = 0;
        #pragma unroll
        for (int j = 0; j < RNB; ++j) {
            u64 kj = shfl64(nkey, j);
            rank += (kj < nkey) ? 1 : 0;
        }
        if (lane < RNB) nkey_l[31 - rank] = nkey;  // descending into slots 96..127
        __syncthreads();

        // bitonic input: e0 = beam (ascending), e1 = [MAX pads | new descending]
        u64 e0 = ((u64)__float_as_uint(bds) << 27)
               | ((u64)(unsigned)(bid * 2 + (bex ? 0 : 1)) << 7)
               | (unsigned)lane;
        u64 e1 = (lane < 32) ? ~0ull : nkey_l[lane - 32];

        // 7-stage bitonic merge, ascending
        {
            u64 lo = e0 < e1 ? e0 : e1;
            u64 hi = e0 < e1 ? e1 : e0;
            e0 = lo; e1 = hi;
        }
        #pragma unroll
        for (int j = 32; j >= 1; j >>= 1) {
            u64 o0 = shflx64(e0, j);
            u64 o1 = shflx64(e1, j);
            bool keepmin = (lane & j) == 0;
            e0 = keepmin ? (e0 < o0 ? e0 : o0) : (e0 > o0 ? e0 : o0);
            e1 = keepmin ? (e1 < o1 ? e1 : o1) : (e1 > o1 ? e1 : o1);
        }

        // decode new beam slot `lane` from e0
        int src = (int)(e0 & 127u);
        int idA = __shfl(bid, src & 63);
        int exA = __shfl(bex, src & 63);
        int idB = __shfl(nid, src & 31);
        int exB = __shfl(kill ? 1 : 0, src & 31);
        bds = __uint_as_float((unsigned)(e0 >> 27));
        bid = (src < 64) ? idA : idB;
        bex = (src < 64) ? exA : exB;
        __syncthreads();
    }

    // ---- outputs: ids (as float, exact for id < 2^24) then dists
    if (lane < KTOP) {
        out[(size_t)b * KTOP + lane] = (float)bid;
        out[(size_t)B * KTOP + (size_t)b * KTOP + lane] = bds;
    }
}

extern "C" void kernel_launch(void* const* d_in, const int* in_sizes, int n_in,
                              void* d_out, int out_size, void* d_ws, size_t ws_size,
                              hipStream_t stream) {
    const float* query   = (const float*)d_in[0];
    const float* storage = (const float*)d_in[1];
    const int*   indices = (const int*)d_in[2];
    const int*   entry   = (const int*)d_in[3];
    int B = in_sizes[0] / DIM;
    float* out = (float*)d_out;
    nsw_search<<<B, 64, 0, stream>>>(query, storage, indices, entry, out, B);
}

// Round 3
// 227.220 us; speedup vs baseline: 1.4682x; 1.2973x over previous
//
#include <hip/hip_runtime.h>
#include <stdint.h>

#define DIM 128
#define RNB 32
#define EFS 64
#define KTOP 10
#define INFD 1e30f

typedef unsigned long long u64;

__device__ __forceinline__ u64 shflx64(u64 v, int m) {
    return (u64)__shfl_xor((long long)v, m, 64);
}
__device__ __forceinline__ u64 shfl64(u64 v, int src) {
    return (u64)__shfl((long long)v, src, 64);
}
// push-permute 64-bit: lane writes v to dest lane (dst_byte/4); unwritten dests get 0
__device__ __forceinline__ u64 dsperm64(int dst_byte, u64 v) {
    int lo = __builtin_amdgcn_ds_permute(dst_byte, (int)(unsigned)(v & 0xffffffffu));
    int hi = __builtin_amdgcn_ds_permute(dst_byte, (int)(unsigned)(v >> 32));
    return ((u64)(unsigned)hi << 32) | (unsigned)lo;
}

// ---------------- exact slow-path merge (validated rounds 1-2) ----------------
__device__ __forceinline__ void bitonic128(u64 &e0, u64 &e1, int lane) {
    #pragma unroll
    for (int k = 2; k <= 128; k <<= 1) {
        #pragma unroll
        for (int j = k >> 1; j >= 1; j >>= 1) {
            if (j == 64) {
                u64 lo = e0 < e1 ? e0 : e1;
                u64 hi = e0 < e1 ? e1 : e0;
                e0 = lo; e1 = hi;
            } else {
                u64 o0 = shflx64(e0, j);
                u64 o1 = shflx64(e1, j);
                int i0 = lane, i1 = lane + 64;
                bool keepmin0 = ((i0 & k) == 0) == ((i0 & j) == 0);
                bool keepmin1 = ((i1 & k) == 0) == ((i1 & j) == 0);
                e0 = keepmin0 ? (e0 < o0 ? e0 : o0) : (e0 > o0 ? e0 : o0);
                e1 = keepmin1 ? (e1 < o1 ? e1 : o1) : (e1 > o1 ? e1 : o1);
            }
        }
    }
}

__device__ __forceinline__ void merge_slow(int n, int lane,
                                           int* ids_s, float* dst_s, int* exp_s,
                                           int* ids2, float* dst2, int* exp2) {
    __syncthreads();
    {
        int i1 = lane + 64;
        u64 e0 = ((u64)(uint32_t)(ids_s[lane] * 2 + (exp_s[lane] ? 0 : 1)) << 32) | (uint32_t)lane;
        u64 e1 = ~0ULL;
        if (i1 < n)
            e1 = ((u64)(uint32_t)(ids_s[i1] * 2 + (exp_s[i1] ? 0 : 1)) << 32) | (uint32_t)i1;
        bitonic128(e0, e1, lane);

        int id0 = -1, id1 = -1; float d0 = INFD, d1 = INFD; int x0 = 1, x1 = 1;
        { int p = (int)(e0 & 0xffffffffu); id0 = ids_s[p]; d0 = dst_s[p]; x0 = exp_s[p]; }
        if (e1 != ~0ULL) { int p = (int)(e1 & 0xffffffffu); id1 = ids_s[p]; d1 = dst_s[p]; x1 = exp_s[p]; }

        int prev0 = __shfl_up(id0, 1);
        int top0  = __shfl(id0, 63);
        int prev1 = __shfl_up(id1, 1);
        bool dup0 = (lane > 0) && (id0 == prev0);
        bool dup1 = (i1 < n) && (id1 == ((lane == 0) ? top0 : prev1));
        if (dup0) { d0 = INFD; x0 = 1; }
        if (dup1) { d1 = INFD; x1 = 1; }

        ids2[lane] = id0; dst2[lane] = d0; exp2[lane] = x0;
        ids2[i1]   = id1; dst2[i1]   = d1; exp2[i1]   = x1;

        u64 f0 = ((u64)__float_as_uint(d0) << 32) | (uint32_t)lane;
        u64 f1 = (i1 < n) ? (((u64)__float_as_uint(d1) << 32) | (uint32_t)i1) : ~0ULL;
        bitonic128(f0, f1, lane);

        int pf = (int)(f0 & 0xffffffffu);
        int idf = ids2[pf]; float df = dst2[pf]; int xf = exp2[pf];
        __syncthreads();
        ids_s[lane] = idf; dst_s[lane] = df; exp_s[lane] = xf;
    }
    __syncthreads();
}

// ---------------------------------------------------------------------------
extern "C" __global__ __launch_bounds__(64, 1)
void nsw_search(const float* __restrict__ query,
                const float* __restrict__ storage,
                const int* __restrict__ indices,
                const int* __restrict__ entry,
                float* __restrict__ out,
                int B) {
    const int b = blockIdx.x;
    const int lane = threadIdx.x;  // 0..63, single wave

    __shared__ __align__(16) float q_s[DIM];
    __shared__ int   ids_s[96];
    __shared__ float dst_s[96];
    __shared__ int   exp_s[96];
    __shared__ int   ids2[128];
    __shared__ float dst2[128];
    __shared__ int   exp2[128];

    q_s[lane]      = query[(size_t)b * DIM + lane];
    q_s[64 + lane] = query[(size_t)b * DIM + 64 + lane];
    ids_s[lane] = entry[(size_t)b * EFS + lane];
    exp_s[lane] = 0;
    __syncthreads();

    // ---- initial distances (exact round-1 chunking, validated)
    #pragma unroll
    for (int p = 0; p < 4; ++p) {
        int g = p * 16 + (lane >> 2), sub = lane & 3;
        int id = ids_s[g];
        const float4* row = (const float4*)(storage + (size_t)id * DIM);
        const float4* q4 = (const float4*)q_s;
        float acc = 0.f;
        #pragma unroll
        for (int c = 0; c < 8; ++c) {
            float4 v = row[sub * 8 + c];
            float4 qv = q4[sub * 8 + c];
            float dx = v.x - qv.x; acc = fmaf(dx, dx, acc);
            dx = v.y - qv.y; acc = fmaf(dx, dx, acc);
            dx = v.z - qv.z; acc = fmaf(dx, dx, acc);
            dx = v.w - qv.w; acc = fmaf(dx, dx, acc);
        }
        acc += __shfl_xor(acc, 1);
        acc += __shfl_xor(acc, 2);
        if (sub == 0) dst_s[g] = acc;
    }

    merge_slow(64, lane, ids_s, dst_s, exp_s, ids2, dst2, exp2);

    int   bid = ids_s[lane];
    float bds = dst_s[lane];
    int   bex = exp_s[lane];

    // q chunk for step distances (sub = lane&7 -> dims [sub*16, sub*16+16))
    float4 qv0, qv1, qv2, qv3;
    {
        const float4* q4 = (const float4*)q_s;
        int sub = lane & 7;
        qv0 = q4[sub * 4 + 0]; qv1 = q4[sub * 4 + 1];
        qv2 = q4[sub * 4 + 2]; qv3 = q4[sub * 4 + 3];
    }

    // ---- step-0 select + neighbor-index load
    int nidx;
    {
        u64 open = __ballot(bex == 0);
        int sel = open ? (int)(__ffsll((long long)open) - 1) : 0;
        int node = __shfl(bid, sel);
        if (lane == sel) bex = 1;
        nidx = indices[(size_t)node * RNB + (lane & 31)];
    }

    // ---- issue storage loads for step 0 (all 16 float4 in flight at once)
    float4 va[4][4];
    #pragma unroll
    for (int p = 0; p < 4; ++p) {
        int g = p * 8 + (lane >> 3);
        int idp = __shfl(nidx, g);
        const float4* row = (const float4*)(storage + (size_t)idp * DIM) + (lane & 7) * 4;
        va[p][0] = row[0]; va[p][1] = row[1]; va[p][2] = row[2]; va[p][3] = row[3];
    }

    for (int step = 0; step < EFS; ++step) {
        // ---- distances from preloaded registers (exact round-2 arithmetic)
        float accs[4];
        #pragma unroll
        for (int p = 0; p < 4; ++p) {
            float acc = 0.f;
            float4 v;
            v = va[p][0];
            { float dx = v.x - qv0.x; acc = fmaf(dx, dx, acc);
              dx = v.y - qv0.y; acc = fmaf(dx, dx, acc);
              dx = v.z - qv0.z; acc = fmaf(dx, dx, acc);
              dx = v.w - qv0.w; acc = fmaf(dx, dx, acc); }
            v = va[p][1];
            { float dx = v.x - qv1.x; acc = fmaf(dx, dx, acc);
              dx = v.y - qv1.y; acc = fmaf(dx, dx, acc);
              dx = v.z - qv1.z; acc = fmaf(dx, dx, acc);
              dx = v.w - qv1.w; acc = fmaf(dx, dx, acc); }
            v = va[p][2];
            { float dx = v.x - qv2.x; acc = fmaf(dx, dx, acc);
              dx = v.y - qv2.y; acc = fmaf(dx, dx, acc);
              dx = v.z - qv2.z; acc = fmaf(dx, dx, acc);
              dx = v.w - qv2.w; acc = fmaf(dx, dx, acc); }
            v = va[p][3];
            { float dx = v.x - qv3.x; acc = fmaf(dx, dx, acc);
              dx = v.y - qv3.y; acc = fmaf(dx, dx, acc);
              dx = v.z - qv3.z; acc = fmaf(dx, dx, acc);
              dx = v.w - qv3.w; acc = fmaf(dx, dx, acc); }
            acc += __shfl_xor(acc, 1);
            acc += __shfl_xor(acc, 2);
            acc += __shfl_xor(acc, 4);
            accs[p] = acc;
        }
        // distribute: lane holds dist of neighbor (lane&31)
        int l8 = (lane & 7) << 3;
        float t0 = __shfl(accs[0], l8), t1 = __shfl(accs[1], l8);
        float t2 = __shfl(accs[2], l8), t3 = __shfl(accs[3], l8);
        int ps = (lane >> 3) & 3;
        float ndt = (ps & 2) ? ((ps & 1) ? t3 : t2) : ((ps & 1) ? t1 : t0);
        int nid = nidx;  // neighbor (lane&31)'s id (upper lanes mirror lower)

        bool has_inf = (__ballot(bds >= INFD) != 0ull);

        if (!has_inf) {
            // ---- fast path (beam: 64 finite dists, unique ids, key-sorted) ----
            // kills: new j dies iff id matches any beam slot or an earlier new slot
            unsigned killmask = 0u;
            #pragma unroll
            for (int j = 0; j < RNB; ++j) {
                int idj = __shfl(nid, j);
                u64 beq = __ballot(bid == idj);
                u64 neq = __ballot(nid == idj);
                u64 kj = beq | (neq & ((1ull << j) - 1ull));
                killmask |= (kj ? 1u : 0u) << j;
            }
            bool kill = (killmask >> (lane & 31)) & 1u;
            float dk = kill ? INFD : ndt;
            // 59-bit composite key: (dist:32 | id*2+(1-exp):20 | idx:7)
            u64 nkey = ((u64)__float_as_uint(dk) << 27)
                     | ((u64)(unsigned)(nid * 2 + 1) << 7)
                     | (unsigned)(64 + lane);

            int rank = 0;
            #pragma unroll
            for (int j = 0; j < RNB; ++j) {
                u64 kj = shfl64(nkey, j);
                rank += (kj < nkey) ? 1 : 0;
            }
            // push new keys descending into lanes 32..63 (lane 63 = min)
            u64 e1p = dsperm64((lane < 32) ? ((63 - rank) << 2) : 0, nkey);
            u64 K_newmin = ((__ballot(!kill) & 0xffffffffull) != 0ull)
                         ? shfl64(e1p, 63) : ~0ull;

            u64 bkey = ((u64)__float_as_uint(bds) << 27)
                     | ((u64)(unsigned)(bid * 2 + (bex ? 0 : 1)) << 7)
                     | (unsigned)lane;
            u64 bo = __ballot(bex == 0);
            int selb = bo ? (int)(__ffsll((long long)bo) - 1) : 0;
            u64 K_bopen = bo ? shfl64(bkey, selb) : ~0ull;
            u64 K_minopen = (K_bopen < K_newmin) ? K_bopen : K_newmin;
            u64 bkey63 = shfl64(bkey, 63);
            // fallback <=> min-open not in merged top-64 <=> all beam keys < it
            bool fallback = (K_minopen > bkey63);
            int node = fallback ? __shfl(bid, 0)
                                : (int)(((unsigned)((K_minopen >> 7) & 0xFFFFFull)) >> 1);

            // EARLY: issue next step's neighbor-index load (hides under merge)
            nidx = indices[(size_t)node * RNB + (lane & 31)];

            // bitonic merge: [beam asc | MAXx32, new desc] -> keep lower half
            u64 e0 = bkey;
            u64 e1 = (lane < 32) ? ~0ull : e1p;
            { u64 lo = e0 < e1 ? e0 : e1; e0 = lo; }
            #pragma unroll
            for (int j = 32; j >= 1; j >>= 1) {
                u64 o0 = shflx64(e0, j);
                bool keepmin = (lane & j) == 0;
                e0 = keepmin ? (e0 < o0 ? e0 : o0) : (e0 > o0 ? e0 : o0);
            }

            // decode beam from key bits (no shuffles needed)
            bds = __uint_as_float((unsigned)(e0 >> 27));
            unsigned key1 = (unsigned)((e0 >> 7) & 0xFFFFFull);
            bid = (int)(key1 >> 1);
            bex = (int)((key1 & 1u) ^ 1u);
            // mark next selected node expanded (matches reference's .at[sel].set)
            if (!fallback && e0 == K_minopen) bex = 1;
        } else {
            // ---- exact slow path (INF tombstones present; rare) ----
            ids_s[lane] = bid; dst_s[lane] = bds; exp_s[lane] = bex;
            if (lane < RNB) { ids_s[64 + lane] = nid; dst_s[64 + lane] = ndt; exp_s[64 + lane] = 0; }
            merge_slow(96, lane, ids_s, dst_s, exp_s, ids2, dst2, exp2);
            bid = ids_s[lane]; bds = dst_s[lane]; bex = exp_s[lane];
            u64 open = __ballot(bex == 0);
            int sel = open ? (int)(__ffsll((long long)open) - 1) : 0;
            int node = __shfl(bid, sel);
            if (lane == sel) bex = 1;
            nidx = indices[(size_t)node * RNB + (lane & 31)];
        }

        // ---- tail: issue next step's storage loads (consumed at next top)
        if (step + 1 < EFS) {
            #pragma unroll
            for (int p = 0; p < 4; ++p) {
                int g = p * 8 + (lane >> 3);
                int idp = __shfl(nidx, g);
                const float4* row = (const float4*)(storage + (size_t)idp * DIM) + (lane & 7) * 4;
                va[p][0] = row[0]; va[p][1] = row[1]; va[p][2] = row[2]; va[p][3] = row[3];
            }
        }
    }

    // ---- outputs: ids (as float, exact for id < 2^24) then dists
    if (lane < KTOP) {
        out[(size_t)b * KTOP + lane] = (float)bid;
        out[(size_t)B * KTOP + (size_t)b * KTOP + lane] = bds;
    }
}

extern "C" void kernel_launch(void* const* d_in, const int* in_sizes, int n_in,
                              void* d_out, int out_size, void* d_ws, size_t ws_size,
                              hipStream_t stream) {
    const float* query   = (const float*)d_in[0];
    const float* storage = (const float*)d_in[1];
    const int*   indices = (const int*)d_in[2];
    const int*   entry   = (const int*)d_in[3];
    int B = in_sizes[0] / DIM;
    float* out = (float*)d_out;
    nsw_search<<<B, 64, 0, stream>>>(query, storage, indices, entry, out, B);
}